// Round 4
// baseline (2913.057 us; speedup 1.0000x reference)
//
#include <hip/hip_runtime.h>
#include <hip/hip_bf16.h>
#include <cstdint>
#include <cstddef>

// ---------------- problem constants ----------------
#define B_SZ    1024
#define L_SEQ   128
#define INSZ    64
#define EMB     256
#define NH      4
#define DH      64
#define QKV3    768
#define NEDGE   16384
#define GHEADS  4
#define GHID    64
#define GOUT    256
#define NCLS    16

#define NCHUNK     8
#define BCHUNK     (B_SZ / NCHUNK)        // 128 batches per chunk
#define ROWS_CHUNK (BCHUNK * L_SEQ)       // 16384 rows per chunk

typedef unsigned short ushort_t;
typedef short bf16x8 __attribute__((ext_vector_type(8)));      // 8 bf16 in 4 VGPRs
typedef float f32x4 __attribute__((ext_vector_type(4)));
typedef ushort_t us4 __attribute__((ext_vector_type(4)));
typedef ushort_t us8 __attribute__((ext_vector_type(8)));

__device__ __forceinline__ ushort_t f32_to_bf16_rne(float x) {
    unsigned u = __float_as_uint(x);
    unsigned r = u + 0x7FFFu + ((u >> 16) & 1u);
    return (ushort_t)(r >> 16);
}
__device__ __forceinline__ float bf16u_to_f32(ushort_t h) {
    return __uint_as_float(((unsigned)h) << 16);
}

// ---------------- weight transpose + fp32->bf16 hi/lo split ----------------
// W [K][N] row-major fp32  ->  WtH/WtL [N][K] bf16 (hi = rne(x), lo = rne(x-hi))
__global__ __launch_bounds__(256) void wsplit_kernel(
    const float* __restrict__ W, ushort_t* __restrict__ WtH,
    ushort_t* __restrict__ WtL, int K, int N)
{
    const int t = blockIdx.x * 256 + threadIdx.x;
    if (t >= K * N) return;
    const int n = t / K, k = t - n * K;
    const float x = W[(size_t)k * N + n];
    const ushort_t hi = f32_to_bf16_rne(x);
    const ushort_t lo = f32_to_bf16_rne(x - bf16u_to_f32(hi));
    WtH[t] = hi;
    WtL[t] = lo;
}

// ---------------- MFMA split-bf16 GEMM: C = A@B + bias (fp32-accurate) ----------------
// A fp32 [M][K] (lda), B pre-split bf16 [N][K] (dense, ld=K), C fp32 [M][ldc].
// Tile 128x128x32. 4 waves in 2x2, each wave 64x64 via 4x4 mfma_16x16x32 tiles.
// 3-term split: hi*hi + lo*hi + hi*lo (drop lo*lo) => ~1e-4 relative accuracy.
// Fragment layouts (m89/m92-verified): A/B lane: row|col = lane&15,
// k = (lane>>4)*8 .. +8 contiguous; C/D: col = lane&15, row = (lane>>4)*4 + reg.
#define AKP 40   // padded LDS K stride (bf16 elems): 80B rows -> <=2-way b128 frag reads

__global__ __launch_bounds__(256) void gemm_mfma_split(
    const float* __restrict__ A, const ushort_t* __restrict__ BtH,
    const ushort_t* __restrict__ BtL, const float* __restrict__ bias,
    float* __restrict__ C, int K, int lda, int ldc)
{
    __shared__ __attribute__((aligned(16))) ushort_t AsH[128][AKP];
    __shared__ __attribute__((aligned(16))) ushort_t AsL[128][AKP];
    __shared__ __attribute__((aligned(16))) ushort_t BsH[128][AKP];
    __shared__ __attribute__((aligned(16))) ushort_t BsL[128][AKP];

    const int tid  = threadIdx.x;
    const int lane = tid & 63;
    const int wv   = tid >> 6;
    const int wm   = (wv >> 1) << 6;      // wave row offset: 0 / 64
    const int wn   = (wv & 1) << 6;       // wave col offset: 0 / 64
    const int fr   = lane & 15;           // row(A)/col(B) within 16-tile
    const int fk   = (lane >> 4) << 3;    // k base: 0,8,16,24
    const size_t brow = (size_t)blockIdx.y << 7;
    const int    bcol = blockIdx.x << 7;

    const int ar = tid >> 3;              // 0..31  (A stage row base, x4 over rr)
    const int ac = (tid & 7) << 2;        // 0..28  (A stage k base, 4 floats)
    const int bn = tid >> 1;              // 0..127 (B stage n row)
    const int bk = (tid & 1) << 4;        // 0 / 16 (B stage k base, 16 bf16)

    f32x4 acc[4][4] = {};

    for (int k0 = 0; k0 < K; k0 += 32) {
        // ---- stage A: 128x32 fp32 -> hi/lo bf16 (8 thr x 4 floats = full 32 k) ----
        #pragma unroll
        for (int rr = 0; rr < 4; ++rr) {
            const int row = ar + (rr << 5);
            const float4 v = *reinterpret_cast<const float4*>(
                &A[(brow + row) * lda + k0 + ac]);
            const ushort_t h0 = f32_to_bf16_rne(v.x);
            const ushort_t h1 = f32_to_bf16_rne(v.y);
            const ushort_t h2 = f32_to_bf16_rne(v.z);
            const ushort_t h3 = f32_to_bf16_rne(v.w);
            const ushort_t l0 = f32_to_bf16_rne(v.x - bf16u_to_f32(h0));
            const ushort_t l1 = f32_to_bf16_rne(v.y - bf16u_to_f32(h1));
            const ushort_t l2 = f32_to_bf16_rne(v.z - bf16u_to_f32(h2));
            const ushort_t l3 = f32_to_bf16_rne(v.w - bf16u_to_f32(h3));
            us4 hv = {h0, h1, h2, h3};
            us4 lv = {l0, l1, l2, l3};
            *reinterpret_cast<us4*>(&AsH[row][ac]) = hv;
            *reinterpret_cast<us4*>(&AsL[row][ac]) = lv;
        }
        // ---- stage B: 128x32 bf16 pre-split [N][K]; 2 thr x 16 bf16 = full 32 k ----
        // (round-2 bug: only 8 of each thread's 16 k-elems were staged)
        {
            const size_t bb = (size_t)(bcol + bn) * K + k0 + bk;
            *reinterpret_cast<us8*>(&BsH[bn][bk]) =
                *reinterpret_cast<const us8*>(&BtH[bb]);
            *reinterpret_cast<us8*>(&BsH[bn][bk + 8]) =
                *reinterpret_cast<const us8*>(&BtH[bb + 8]);
            *reinterpret_cast<us8*>(&BsL[bn][bk]) =
                *reinterpret_cast<const us8*>(&BtL[bb]);
            *reinterpret_cast<us8*>(&BsL[bn][bk + 8]) =
                *reinterpret_cast<const us8*>(&BtL[bb + 8]);
        }
        __syncthreads();

        bf16x8 aH[4], aL[4], bH[4], bL[4];
        #pragma unroll
        for (int i = 0; i < 4; ++i) {
            aH[i] = *reinterpret_cast<const bf16x8*>(&AsH[wm + (i << 4) + fr][fk]);
            aL[i] = *reinterpret_cast<const bf16x8*>(&AsL[wm + (i << 4) + fr][fk]);
            bH[i] = *reinterpret_cast<const bf16x8*>(&BsH[wn + (i << 4) + fr][fk]);
            bL[i] = *reinterpret_cast<const bf16x8*>(&BsL[wn + (i << 4) + fr][fk]);
        }
        #pragma unroll
        for (int i = 0; i < 4; ++i) {
            #pragma unroll
            for (int j = 0; j < 4; ++j) {
                acc[i][j] = __builtin_amdgcn_mfma_f32_16x16x32_bf16(
                    aH[i], bH[j], acc[i][j], 0, 0, 0);
                acc[i][j] = __builtin_amdgcn_mfma_f32_16x16x32_bf16(
                    aL[i], bH[j], acc[i][j], 0, 0, 0);
                acc[i][j] = __builtin_amdgcn_mfma_f32_16x16x32_bf16(
                    aH[i], bL[j], acc[i][j], 0, 0, 0);
            }
        }
        __syncthreads();
    }

    // ---- epilogue: C/D layout col=lane&15, row=(lane>>4)*4+r ----
    const int r4 = (lane >> 4) << 2;
    #pragma unroll
    for (int j = 0; j < 4; ++j) {
        const int col = bcol + wn + (j << 4) + fr;
        const float bv = bias ? bias[col] : 0.f;
        #pragma unroll
        for (int i = 0; i < 4; ++i) {
            #pragma unroll
            for (int r = 0; r < 4; ++r) {
                const size_t row = brow + wm + (i << 4) + r4 + r;
                C[row * ldc + col] = acc[i][j][r] + bv;
            }
        }
    }
}

// ---------------- small tiled fp32 GEMM: 64x64x32, 4x4/thread (GAT) ----------------
#define BM 64
#define BN 64
#define BK 32

__global__ __launch_bounds__(256) void gemm_bias(
    const float* __restrict__ A, const float* __restrict__ Bm,
    const float* __restrict__ bias, float* __restrict__ C,
    int M, int N, int K, int lda, int ldb, int ldc)
{
    __shared__ float As[BK][BM + 4];   // transposed: As[k][m], padded
    __shared__ float Bs[BK][BN];
    const int tid = threadIdx.x;
    const int tx = tid & 15, ty = tid >> 4;
    const int brow = blockIdx.y * BM, bcol = blockIdx.x * BN;

    float acc[4][4] = {{0.f, 0.f, 0.f, 0.f}, {0.f, 0.f, 0.f, 0.f},
                       {0.f, 0.f, 0.f, 0.f}, {0.f, 0.f, 0.f, 0.f}};

    for (int k0 = 0; k0 < K; k0 += BK) {
        {   // A tile: 64 rows x 32 k, store transposed
            const int r  = tid >> 3;          // 0..31
            const int c4 = (tid & 7) << 2;    // 0..28
            #pragma unroll
            for (int rr = 0; rr < 2; ++rr) {
                const int row = r + (rr << 5);
                const float4 v = *reinterpret_cast<const float4*>(
                    &A[(size_t)(brow + row) * lda + k0 + c4]);
                As[c4 + 0][row] = v.x;
                As[c4 + 1][row] = v.y;
                As[c4 + 2][row] = v.z;
                As[c4 + 3][row] = v.w;
            }
        }
        {   // B tile: 32 k x 64 cols
            const int r  = tid >> 4;          // 0..15
            const int c4 = tx << 2;           // 0..60
            #pragma unroll
            for (int rr = 0; rr < 2; ++rr) {
                const int row = r + (rr << 4);
                *reinterpret_cast<float4*>(&Bs[row][c4]) =
                    *reinterpret_cast<const float4*>(
                        &Bm[(size_t)(k0 + row) * ldb + bcol + c4]);
            }
        }
        __syncthreads();
        #pragma unroll
        for (int k = 0; k < BK; ++k) {
            const float4 av = *reinterpret_cast<const float4*>(&As[k][ty << 2]);
            const float4 bv = *reinterpret_cast<const float4*>(&Bs[k][tx << 2]);
            acc[0][0] += av.x * bv.x; acc[0][1] += av.x * bv.y;
            acc[0][2] += av.x * bv.z; acc[0][3] += av.x * bv.w;
            acc[1][0] += av.y * bv.x; acc[1][1] += av.y * bv.y;
            acc[1][2] += av.y * bv.z; acc[1][3] += av.y * bv.w;
            acc[2][0] += av.z * bv.x; acc[2][1] += av.z * bv.y;
            acc[2][2] += av.z * bv.z; acc[2][3] += av.z * bv.w;
            acc[3][0] += av.w * bv.x; acc[3][1] += av.w * bv.y;
            acc[3][2] += av.w * bv.z; acc[3][3] += av.w * bv.w;
        }
        __syncthreads();
    }

    float b0 = 0.f, b1 = 0.f, b2 = 0.f, b3 = 0.f;
    if (bias) {
        const int col = bcol + (tx << 2);
        b0 = bias[col]; b1 = bias[col + 1]; b2 = bias[col + 2]; b3 = bias[col + 3];
    }
    #pragma unroll
    for (int i = 0; i < 4; ++i) {
        const int row = brow + (ty << 2) + i;
        float4 o;
        o.x = acc[i][0] + b0; o.y = acc[i][1] + b1;
        o.z = acc[i][2] + b2; o.w = acc[i][3] + b3;
        *reinterpret_cast<float4*>(&C[(size_t)row * ldc + bcol + (tx << 2)]) = o;
    }
}

// ---------------- fused masked attention (fp32) ----------------
// One block per (local batch, head, 32-row q-chunk). qkv layout [rows, 768],
// q cols [0,256), k cols [256,512), v cols [512,768); head h owns 64 cols.
__global__ __launch_bounds__(256) void attn_kernel(
    const float* __restrict__ qkv, const int* __restrict__ lengths,
    float* __restrict__ out, int b0)
{
    const int bid = blockIdx.x;
    const int lb  = bid >> 4;
    const int h   = (bid >> 2) & 3;
    const int qc  = bid & 3;
    const int len = lengths[b0 + lb];
    const int tid = threadIdx.x;

    __shared__ float Qs[32][DH + 4];
    __shared__ float Kt[DH][36];           // transposed K chunk: Kt[d][j]
    __shared__ float Vs[32][DH + 4];
    __shared__ float Ss[32][L_SEQ + 4];

    const size_t rowbase = (size_t)lb * L_SEQ;
    const int q0 = qc * 32;

    {   // load Q chunk, pre-scaled by 1/sqrt(dh)
        const int r  = tid >> 4;
        const int c4 = (tid & 15) << 2;
        #pragma unroll
        for (int rr = 0; rr < 2; ++rr) {
            const int row = r + (rr << 4);
            float4 v = *reinterpret_cast<const float4*>(
                &qkv[(rowbase + q0 + row) * QKV3 + h * DH + c4]);
            v.x *= 0.125f; v.y *= 0.125f; v.z *= 0.125f; v.w *= 0.125f;
            *reinterpret_cast<float4*>(&Qs[row][c4]) = v;
        }
    }

    // ---- S = Q K^T over 4 key chunks of 32 ----
    for (int kc = 0; kc < 4; ++kc) {
        {   // load K chunk transposed
            const int r  = tid >> 4;
            const int c4 = (tid & 15) << 2;
            #pragma unroll
            for (int rr = 0; rr < 2; ++rr) {
                const int row = r + (rr << 4);
                const float4 v = *reinterpret_cast<const float4*>(
                    &qkv[(rowbase + kc * 32 + row) * QKV3 + EMB + h * DH + c4]);
                Kt[c4 + 0][row] = v.x;
                Kt[c4 + 1][row] = v.y;
                Kt[c4 + 2][row] = v.z;
                Kt[c4 + 3][row] = v.w;
            }
        }
        __syncthreads();
        const int si  = tid >> 3;
        const int sj0 = (tid & 7) << 2;
        float s0 = 0.f, s1 = 0.f, s2 = 0.f, s3 = 0.f;
        #pragma unroll
        for (int d = 0; d < DH; ++d) {
            const float qv = Qs[si][d];
            const float4 kv = *reinterpret_cast<const float4*>(&Kt[d][sj0]);
            s0 += qv * kv.x; s1 += qv * kv.y; s2 += qv * kv.z; s3 += qv * kv.w;
        }
        Ss[si][kc * 32 + sj0 + 0] = s0;
        Ss[si][kc * 32 + sj0 + 1] = s1;
        Ss[si][kc * 32 + sj0 + 2] = s2;
        Ss[si][kc * 32 + sj0 + 3] = s3;
        __syncthreads();
    }

    // ---- masked softmax, 8 threads per row ----
    {
        const int r    = tid >> 3;
        const int lane = tid & 7;
        float m = -3.0e38f;
        #pragma unroll
        for (int jj = 0; jj < 16; ++jj) {
            const int j = lane + (jj << 3);
            if (j < len) m = fmaxf(m, Ss[r][j]);
        }
        #pragma unroll
        for (int o = 1; o < 8; o <<= 1) m = fmaxf(m, __shfl_xor(m, o, 8));
        float sum = 0.f;
        float ev[16];
        #pragma unroll
        for (int jj = 0; jj < 16; ++jj) {
            const int j = lane + (jj << 3);
            float e = 0.f;
            if (j < len) { e = __expf(Ss[r][j] - m); }
            ev[jj] = e;
            sum += e;
        }
        #pragma unroll
        for (int o = 1; o < 8; o <<= 1) sum += __shfl_xor(sum, o, 8);
        const float inv = 1.f / sum;
        #pragma unroll
        for (int jj = 0; jj < 16; ++jj) {
            const int j = lane + (jj << 3);
            Ss[r][j] = ev[jj] * inv;
        }
    }
    __syncthreads();

    // ---- O = P V over 4 value chunks ----
    const int oi  = tid >> 3;
    const int oc0 = (tid & 7) << 3;
    float o[8] = {0.f, 0.f, 0.f, 0.f, 0.f, 0.f, 0.f, 0.f};
    for (int kc = 0; kc < 4; ++kc) {
        {   // load V chunk
            const int r  = tid >> 4;
            const int c4 = (tid & 15) << 2;
            #pragma unroll
            for (int rr = 0; rr < 2; ++rr) {
                const int row = r + (rr << 4);
                *reinterpret_cast<float4*>(&Vs[row][c4]) =
                    *reinterpret_cast<const float4*>(
                        &qkv[(rowbase + kc * 32 + row) * QKV3 + 2 * EMB + h * DH + c4]);
            }
        }
        __syncthreads();
        #pragma unroll
        for (int kk = 0; kk < 32; ++kk) {
            const float p = Ss[oi][kc * 32 + kk];
            const float4 v0 = *reinterpret_cast<const float4*>(&Vs[kk][oc0]);
            const float4 v1 = *reinterpret_cast<const float4*>(&Vs[kk][oc0 + 4]);
            o[0] += p * v0.x; o[1] += p * v0.y; o[2] += p * v0.z; o[3] += p * v0.w;
            o[4] += p * v1.x; o[5] += p * v1.y; o[6] += p * v1.z; o[7] += p * v1.w;
        }
        __syncthreads();
    }
    {
        float4 w0, w1;
        w0.x = o[0]; w0.y = o[1]; w0.z = o[2]; w0.w = o[3];
        w1.x = o[4]; w1.y = o[5]; w1.z = o[6]; w1.w = o[7];
        float* dst = &out[(rowbase + q0 + oi) * EMB + h * DH + oc0];
        *reinterpret_cast<float4*>(dst)     = w0;
        *reinterpret_cast<float4*>(dst + 4) = w1;
    }
}

// ---------------- LayerNorm (optional residual, optional col-bias, optional relu) ----------------
__device__ __forceinline__ float block_sum256(float v, float* red) {
    #pragma unroll
    for (int o = 32; o >= 1; o >>= 1) v += __shfl_down(v, o, 64);
    const int wid = threadIdx.x >> 6;
    if ((threadIdx.x & 63) == 0) red[wid] = v;
    __syncthreads();
    const float r = red[0] + red[1] + red[2] + red[3];
    __syncthreads();
    return r;
}

__global__ __launch_bounds__(256) void ln_kernel(
    const float* __restrict__ x, const float* __restrict__ res,
    const float* __restrict__ bias, const float* __restrict__ g,
    const float* __restrict__ beta, float* __restrict__ out, int relu)
{
    __shared__ float red[4];
    const size_t row = blockIdx.x;
    const int c = threadIdx.x;
    float v = x[row * 256 + c];
    if (res)  v += res[row * 256 + c];
    if (bias) v += bias[c];
    const float mu = block_sum256(v, red) * (1.f / 256.f);
    const float d  = v - mu;
    const float var = block_sum256(d * d, red) * (1.f / 256.f);
    float o = d * rsqrtf(var + 1e-5f) * g[c] + beta[c];
    if (relu) o = fmaxf(o, 0.f);
    out[row * 256 + c] = o;
}

// ---------------- masked mean pooling ----------------
__global__ __launch_bounds__(256) void pool_kernel(
    const float* __restrict__ h, const int* __restrict__ lengths,
    float* __restrict__ pooled)
{
    const int b = blockIdx.x;
    const int c = threadIdx.x;
    const int len = lengths[b];
    float s = 0.f;
    for (int l = 0; l < len; ++l)
        s += h[((size_t)b * L_SEQ + l) * EMB + c];
    pooled[(size_t)b * EMB + c] = s / (float)len;
}

// ---------------- GAT: per-node attention coefficients ----------------
__global__ __launch_bounds__(256) void gat_sd_kernel(
    const float* __restrict__ xh, const float* __restrict__ asrc,
    const float* __restrict__ adst, float* __restrict__ sbuf,
    float* __restrict__ dbuf)
{
    const int n  = blockIdx.x;
    const int hd = threadIdx.x >> 6;
    const int d  = threadIdx.x & 63;
    const float xv = xh[(size_t)n * GOUT + hd * GHID + d];
    float sv = xv * asrc[hd * GHID + d];
    float dv = xv * adst[hd * GHID + d];
    #pragma unroll
    for (int o = 32; o >= 1; o >>= 1) {
        sv += __shfl_down(sv, o, 64);
        dv += __shfl_down(dv, o, 64);
    }
    if (d == 0) {
        sbuf[n * GHEADS + hd] = sv;
        dbuf[n * GHEADS + hd] = dv;
    }
}

__device__ __forceinline__ unsigned fenc(float f) {
    const unsigned u = __float_as_uint(f);
    return (u & 0x80000000u) ? ~u : (u | 0x80000000u);
}
__device__ __forceinline__ float fdec(unsigned u) {
    return __uint_as_float((u & 0x80000000u) ? (u ^ 0x80000000u) : ~u);
}

__global__ __launch_bounds__(256) void gat_edge_max(
    const int* __restrict__ ei, const float* __restrict__ sbuf,
    const float* __restrict__ dbuf, unsigned* __restrict__ emaxU)
{
    const int t = blockIdx.x * 256 + threadIdx.x;
    const int e = t >> 2, hd = t & 3;
    const int src = ei[e], dst = ei[NEDGE + e];
    float ev = sbuf[src * GHEADS + hd] + dbuf[dst * GHEADS + hd];
    ev = ev > 0.f ? ev : 0.2f * ev;
    atomicMax(&emaxU[dst * GHEADS + hd], fenc(ev));
}

__global__ __launch_bounds__(256) void gat_edge_exp(
    const int* __restrict__ ei, const float* __restrict__ sbuf,
    const float* __restrict__ dbuf, const unsigned* __restrict__ emaxU,
    float* __restrict__ eebuf, float* __restrict__ denom)
{
    const int t = blockIdx.x * 256 + threadIdx.x;
    const int e = t >> 2, hd = t & 3;
    const int src = ei[e], dst = ei[NEDGE + e];
    float ev = sbuf[src * GHEADS + hd] + dbuf[dst * GHEADS + hd];
    ev = ev > 0.f ? ev : 0.2f * ev;
    const float ee = __expf(ev - fdec(emaxU[dst * GHEADS + hd]));
    eebuf[t] = ee;
    atomicAdd(&denom[dst * GHEADS + hd], ee);
}

__global__ __launch_bounds__(256) void gat_edge_scatter(
    const int* __restrict__ ei, const float* __restrict__ eebuf,
    const float* __restrict__ denom, const float* __restrict__ xh,
    float* __restrict__ gacc)
{
    const int t   = blockIdx.x * 256 + threadIdx.x;   // e*16 + hd*4 + grp
    const int e   = t >> 4;
    const int hd  = (t >> 2) & 3;
    const int grp = t & 3;
    const int src = ei[e], dst = ei[NEDGE + e];
    const float coef = eebuf[e * GHEADS + hd] / (denom[dst * GHEADS + hd] + 1e-16f);
    const int so = src * GOUT + hd * GHID + grp * 16;
    const int doo = dst * GOUT + hd * GHID + grp * 16;
    #pragma unroll
    for (int i = 0; i < 16; ++i)
        atomicAdd(&gacc[doo + i], xh[so + i] * coef);
}

// ---------------- final FC ----------------
__global__ __launch_bounds__(256) void fc_kernel(
    const float* __restrict__ g, const float* __restrict__ w,
    const float* __restrict__ b, float* __restrict__ out)
{
    const int node = blockIdx.x * 16 + (threadIdx.x >> 4);
    const int c    = threadIdx.x & 15;
    float s = 0.f;
    for (int k = 0; k < 256; ++k)
        s += g[(size_t)node * 256 + k] * w[k * NCLS + c];
    out[node * NCLS + c] = s + b[c];
}

// ---------------- host orchestration ----------------
extern "C" void kernel_launch(void* const* d_in, const int* in_sizes, int n_in,
                              void* d_out, int out_size, void* d_ws, size_t ws_size,
                              hipStream_t stream)
{
    const float* x        = (const float*)d_in[0];
    const int*   lengths  = (const int*)d_in[1];
    const int*   eidx     = (const int*)d_in[2];
    const float* in_w     = (const float*)d_in[3];
    const float* in_b     = (const float*)d_in[4];
    const float* wqkv[2]  = {(const float*)d_in[5], (const float*)d_in[9]};
    const float* bqkv[2]  = {(const float*)d_in[6], (const float*)d_in[10]};
    const float* wo[2]    = {(const float*)d_in[7], (const float*)d_in[11]};
    const float* bo[2]    = {(const float*)d_in[8], (const float*)d_in[12]};
    const float* ln_g[2]  = {(const float*)d_in[13], (const float*)d_in[15]};
    const float* ln_b[2]  = {(const float*)d_in[14], (const float*)d_in[16]};
    const float* gat_w[2]    = {(const float*)d_in[17], (const float*)d_in[21]};
    const float* gat_asrc[2] = {(const float*)d_in[18], (const float*)d_in[22]};
    const float* gat_adst[2] = {(const float*)d_in[19], (const float*)d_in[23]};
    const float* gat_bias[2] = {(const float*)d_in[20], (const float*)d_in[24]};
    const float* lng_g[2] = {(const float*)d_in[25], (const float*)d_in[27]};
    const float* lng_b[2] = {(const float*)d_in[26], (const float*)d_in[28]};
    const float* fc_w     = (const float*)d_in[29];
    const float* fc_b     = (const float*)d_in[30];
    float* outp = (float*)d_out;

    // ---- workspace layout (floats) ----
    float* W = (float*)d_ws;
    float* Hbuf   = W;                       // 131072*256 = 33,554,432
    float* QKVc   = Hbuf + (size_t)33554432; // 16384*768  = 12,582,912
    float* Ac     = QKVc + (size_t)12582912; // 16384*256  =  4,194,304
    float* Pc     = Ac   + (size_t)4194304;  // 16384*256  =  4,194,304
    float* pooled = Pc   + (size_t)4194304;  // 1024*256   =    262,144
    float* xh     = pooled + (size_t)262144;
    float* g1     = xh   + (size_t)262144;
    float* gacc   = g1   + (size_t)262144;
    float* sbuf   = gacc + (size_t)262144;   // 4096
    float* dbuf   = sbuf + 4096;             // 4096
    unsigned* emaxU = (unsigned*)(dbuf + 4096); // 4096
    float* denom  = (float*)(emaxU + 4096);  // 4096
    float* eebuf  = denom + 4096;            // 65536
    // bf16 hi/lo transposed-weight area (16B-aligned: offset is multiple of 4 floats)
    ushort_t* us = (ushort_t*)(eebuf + 65536);
    ushort_t* inwtH   = us;                  // 256*64
    ushort_t* inwtL   = inwtH + 16384;
    ushort_t* qkvtH0  = inwtL + 16384;       // 768*256
    ushort_t* qkvtL0  = qkvtH0 + 196608;
    ushort_t* qkvtH1  = qkvtL0 + 196608;
    ushort_t* qkvtL1  = qkvtH1 + 196608;
    ushort_t* wotH0   = qkvtL1 + 196608;     // 256*256
    ushort_t* wotL0   = wotH0 + 65536;
    ushort_t* wotH1   = wotL0 + 65536;
    ushort_t* wotL1   = wotH1 + 65536;
    ushort_t* qkvtH[2] = {qkvtH0, qkvtH1};
    ushort_t* qkvtL[2] = {qkvtL0, qkvtL1};
    ushort_t* wotH[2]  = {wotH0, wotH1};
    ushort_t* wotL[2]  = {wotL0, wotL1};

    // ---- per-call weight transpose + split (cheap; graph-safe, idempotent) ----
    wsplit_kernel<<<(INSZ * EMB + 255) / 256, 256, 0, stream>>>(
        in_w, inwtH, inwtL, INSZ, EMB);
    for (int l = 0; l < 2; ++l) {
        wsplit_kernel<<<(EMB * QKV3 + 255) / 256, 256, 0, stream>>>(
            wqkv[l], qkvtH[l], qkvtL[l], EMB, QKV3);
        wsplit_kernel<<<(EMB * EMB + 255) / 256, 256, 0, stream>>>(
            wo[l], wotH[l], wotL[l], EMB, EMB);
    }

    // ---- input projection: H = x @ in_w + in_b (MFMA split) ----
    gemm_mfma_split<<<dim3(EMB / 128, (B_SZ * L_SEQ) / 128), 256, 0, stream>>>(
        x, inwtH, inwtL, in_b, Hbuf, INSZ, INSZ, EMB);

    // ---- two transformer layers, chunked over batch ----
    for (int layer = 0; layer < 2; ++layer) {
        for (int ck = 0; ck < NCHUNK; ++ck) {
            float* Hc = Hbuf + (size_t)ck * ROWS_CHUNK * EMB;
            gemm_mfma_split<<<dim3(QKV3 / 128, ROWS_CHUNK / 128), 256, 0, stream>>>(
                Hc, qkvtH[layer], qkvtL[layer], bqkv[layer], QKVc,
                EMB, EMB, QKV3);
            attn_kernel<<<BCHUNK * NH * 4, 256, 0, stream>>>(
                QKVc, lengths, Ac, ck * BCHUNK);
            gemm_mfma_split<<<dim3(EMB / 128, ROWS_CHUNK / 128), 256, 0, stream>>>(
                Ac, wotH[layer], wotL[layer], bo[layer], Pc,
                EMB, EMB, EMB);
            ln_kernel<<<ROWS_CHUNK, 256, 0, stream>>>(
                Hc, Pc, nullptr, ln_g[layer], ln_b[layer], Hc, 0);
        }
    }

    // ---- masked mean pooling ----
    pool_kernel<<<B_SZ, 256, 0, stream>>>(Hbuf, lengths, pooled);

    // ---- two GAT layers (fp32; tiny) ----
    const float* gin = pooled;
    float* gout_ln[2] = {g1, pooled};  // gat2's LN output reuses pooled
    for (int layer = 0; layer < 2; ++layer) {
        gemm_bias<<<dim3(GOUT / BN, B_SZ / BM), 256, 0, stream>>>(
            gin, gat_w[layer], nullptr, xh, B_SZ, GOUT, GOUT, GOUT, GOUT, GOUT);
        gat_sd_kernel<<<B_SZ, 256, 0, stream>>>(
            xh, gat_asrc[layer], gat_adst[layer], sbuf, dbuf);
        hipMemsetAsync(emaxU, 0, B_SZ * GHEADS * sizeof(unsigned), stream);
        hipMemsetAsync(denom, 0, B_SZ * GHEADS * sizeof(float), stream);
        hipMemsetAsync(gacc, 0, (size_t)B_SZ * GOUT * sizeof(float), stream);
        gat_edge_max<<<(NEDGE * GHEADS) / 256, 256, 0, stream>>>(
            eidx, sbuf, dbuf, emaxU);
        gat_edge_exp<<<(NEDGE * GHEADS) / 256, 256, 0, stream>>>(
            eidx, sbuf, dbuf, emaxU, eebuf, denom);
        gat_edge_scatter<<<(NEDGE * GHEADS * 4) / 256, 256, 0, stream>>>(
            eidx, eebuf, denom, xh, gacc);
        ln_kernel<<<B_SZ, 256, 0, stream>>>(
            gacc, nullptr, gat_bias[layer], lng_g[layer], lng_b[layer],
            gout_ln[layer], 1);
        gin = gout_ln[layer];
    }

    // ---- final FC ----
    fc_kernel<<<B_SZ / 16, 256, 0, stream>>>(pooled, fc_w, fc_b, outp);
}

// Round 8
// 2078.145 us; speedup vs baseline: 1.4018x; 1.4018x over previous
//
#include <hip/hip_runtime.h>
#include <hip/hip_bf16.h>
#include <cstdint>
#include <cstddef>

// ---------------- problem constants ----------------
#define B_SZ    1024
#define L_SEQ   128
#define INSZ    64
#define EMB     256
#define NH      4
#define DH      64
#define QKV3    768
#define NEDGE   16384
#define GHEADS  4
#define GHID    64
#define GOUT    256
#define NCLS    16

#define NCHUNK     8
#define BCHUNK     (B_SZ / NCHUNK)        // 128 batches per chunk
#define ROWS_CHUNK (BCHUNK * L_SEQ)       // 16384 rows per chunk

typedef unsigned short ushort_t;
typedef short bf16x8 __attribute__((ext_vector_type(8)));      // 8 bf16 in 4 VGPRs
typedef float f32x4 __attribute__((ext_vector_type(4)));
typedef ushort_t us4 __attribute__((ext_vector_type(4)));
typedef ushort_t us8 __attribute__((ext_vector_type(8)));

__device__ __forceinline__ ushort_t f32_to_bf16_rne(float x) {
    unsigned u = __float_as_uint(x);
    unsigned r = u + 0x7FFFu + ((u >> 16) & 1u);
    return (ushort_t)(r >> 16);
}
__device__ __forceinline__ float bf16u_to_f32(ushort_t h) {
    return __uint_as_float(((unsigned)h) << 16);
}

// ---------------- weight transpose + fp32->bf16 hi/lo split ----------------
__global__ __launch_bounds__(256) void wsplit_kernel(
    const float* __restrict__ W, ushort_t* __restrict__ WtH,
    ushort_t* __restrict__ WtL, int K, int N)
{
    const int t = blockIdx.x * 256 + threadIdx.x;
    if (t >= K * N) return;
    const int n = t / K, k = t - n * K;
    const float x = W[(size_t)k * N + n];
    const ushort_t hi = f32_to_bf16_rne(x);
    const ushort_t lo = f32_to_bf16_rne(x - bf16u_to_f32(hi));
    WtH[t] = hi;
    WtL[t] = lo;
}

// ---------------- MFMA split-bf16 GEMM: C = A@B + bias (fp32-accurate) ----------------
#define AKP 40   // padded LDS K stride (bf16): 80B rows -> <=2-way b128 frag reads

__global__ __launch_bounds__(256) void gemm_mfma_split(
    const float* __restrict__ A, const ushort_t* __restrict__ BtH,
    const ushort_t* __restrict__ BtL, const float* __restrict__ bias,
    float* __restrict__ C, int K, int lda, int ldc)
{
    __shared__ __attribute__((aligned(16))) ushort_t AsH[128][AKP];
    __shared__ __attribute__((aligned(16))) ushort_t AsL[128][AKP];
    __shared__ __attribute__((aligned(16))) ushort_t BsH[128][AKP];
    __shared__ __attribute__((aligned(16))) ushort_t BsL[128][AKP];

    const int tid  = threadIdx.x;
    const int lane = tid & 63;
    const int wv   = tid >> 6;
    const int wm   = (wv >> 1) << 6;
    const int wn   = (wv & 1) << 6;
    const int fr   = lane & 15;
    const int fk   = (lane >> 4) << 3;
    const size_t brow = (size_t)blockIdx.y << 7;
    const int    bcol = blockIdx.x << 7;

    const int ar = tid >> 3;
    const int ac = (tid & 7) << 2;
    const int bn = tid >> 1;
    const int bk = (tid & 1) << 4;

    f32x4 acc[4][4] = {};

    for (int k0 = 0; k0 < K; k0 += 32) {
        #pragma unroll
        for (int rr = 0; rr < 4; ++rr) {
            const int row = ar + (rr << 5);
            const float4 v = *reinterpret_cast<const float4*>(
                &A[(brow + row) * lda + k0 + ac]);
            const ushort_t h0 = f32_to_bf16_rne(v.x);
            const ushort_t h1 = f32_to_bf16_rne(v.y);
            const ushort_t h2 = f32_to_bf16_rne(v.z);
            const ushort_t h3 = f32_to_bf16_rne(v.w);
            const ushort_t l0 = f32_to_bf16_rne(v.x - bf16u_to_f32(h0));
            const ushort_t l1 = f32_to_bf16_rne(v.y - bf16u_to_f32(h1));
            const ushort_t l2 = f32_to_bf16_rne(v.z - bf16u_to_f32(h2));
            const ushort_t l3 = f32_to_bf16_rne(v.w - bf16u_to_f32(h3));
            us4 hv = {h0, h1, h2, h3};
            us4 lv = {l0, l1, l2, l3};
            *reinterpret_cast<us4*>(&AsH[row][ac]) = hv;
            *reinterpret_cast<us4*>(&AsL[row][ac]) = lv;
        }
        {
            const size_t bb = (size_t)(bcol + bn) * K + k0 + bk;
            *reinterpret_cast<us8*>(&BsH[bn][bk]) =
                *reinterpret_cast<const us8*>(&BtH[bb]);
            *reinterpret_cast<us8*>(&BsH[bn][bk + 8]) =
                *reinterpret_cast<const us8*>(&BtH[bb + 8]);
            *reinterpret_cast<us8*>(&BsL[bn][bk]) =
                *reinterpret_cast<const us8*>(&BtL[bb]);
            *reinterpret_cast<us8*>(&BsL[bn][bk + 8]) =
                *reinterpret_cast<const us8*>(&BtL[bb + 8]);
        }
        __syncthreads();

        bf16x8 aH[4], aL[4], bH[4], bL[4];
        #pragma unroll
        for (int i = 0; i < 4; ++i) {
            aH[i] = *reinterpret_cast<const bf16x8*>(&AsH[wm + (i << 4) + fr][fk]);
            aL[i] = *reinterpret_cast<const bf16x8*>(&AsL[wm + (i << 4) + fr][fk]);
            bH[i] = *reinterpret_cast<const bf16x8*>(&BsH[wn + (i << 4) + fr][fk]);
            bL[i] = *reinterpret_cast<const bf16x8*>(&BsL[wn + (i << 4) + fr][fk]);
        }
        #pragma unroll
        for (int i = 0; i < 4; ++i) {
            #pragma unroll
            for (int j = 0; j < 4; ++j) {
                acc[i][j] = __builtin_amdgcn_mfma_f32_16x16x32_bf16(
                    aH[i], bH[j], acc[i][j], 0, 0, 0);
                acc[i][j] = __builtin_amdgcn_mfma_f32_16x16x32_bf16(
                    aL[i], bH[j], acc[i][j], 0, 0, 0);
                acc[i][j] = __builtin_amdgcn_mfma_f32_16x16x32_bf16(
                    aH[i], bL[j], acc[i][j], 0, 0, 0);
            }
        }
        __syncthreads();
    }

    const int r4 = (lane >> 4) << 2;
    #pragma unroll
    for (int j = 0; j < 4; ++j) {
        const int col = bcol + wn + (j << 4) + fr;
        const float bv = bias ? bias[col] : 0.f;
        #pragma unroll
        for (int i = 0; i < 4; ++i) {
            #pragma unroll
            for (int r = 0; r < 4; ++r) {
                const size_t row = brow + wm + (i << 4) + r4 + r;
                C[row * ldc + col] = acc[i][j][r] + bv;
            }
        }
    }
}

// ---------------- small tiled fp32 GEMM: 64x64x32 (GAT linear) ----------------
#define BM 64
#define BN 64
#define BK 32

__global__ __launch_bounds__(256) void gemm_bias(
    const float* __restrict__ A, const float* __restrict__ Bm,
    const float* __restrict__ bias, float* __restrict__ C,
    int M, int N, int K, int lda, int ldb, int ldc)
{
    __shared__ float As[BK][BM + 4];
    __shared__ float Bs[BK][BN];
    const int tid = threadIdx.x;
    const int tx = tid & 15, ty = tid >> 4;
    const int brow = blockIdx.y * BM, bcol = blockIdx.x * BN;

    float acc[4][4] = {{0.f, 0.f, 0.f, 0.f}, {0.f, 0.f, 0.f, 0.f},
                       {0.f, 0.f, 0.f, 0.f}, {0.f, 0.f, 0.f, 0.f}};

    for (int k0 = 0; k0 < K; k0 += BK) {
        {
            const int r  = tid >> 3;
            const int c4 = (tid & 7) << 2;
            #pragma unroll
            for (int rr = 0; rr < 2; ++rr) {
                const int row = r + (rr << 5);
                const float4 v = *reinterpret_cast<const float4*>(
                    &A[(size_t)(brow + row) * lda + k0 + c4]);
                As[c4 + 0][row] = v.x;
                As[c4 + 1][row] = v.y;
                As[c4 + 2][row] = v.z;
                As[c4 + 3][row] = v.w;
            }
        }
        {
            const int r  = tid >> 4;
            const int c4 = tx << 2;
            #pragma unroll
            for (int rr = 0; rr < 2; ++rr) {
                const int row = r + (rr << 4);
                *reinterpret_cast<float4*>(&Bs[row][c4]) =
                    *reinterpret_cast<const float4*>(
                        &Bm[(size_t)(k0 + row) * ldb + bcol + c4]);
            }
        }
        __syncthreads();
        #pragma unroll
        for (int k = 0; k < BK; ++k) {
            const float4 av = *reinterpret_cast<const float4*>(&As[k][ty << 2]);
            const float4 bv = *reinterpret_cast<const float4*>(&Bs[k][tx << 2]);
            acc[0][0] += av.x * bv.x; acc[0][1] += av.x * bv.y;
            acc[0][2] += av.x * bv.z; acc[0][3] += av.x * bv.w;
            acc[1][0] += av.y * bv.x; acc[1][1] += av.y * bv.y;
            acc[1][2] += av.y * bv.z; acc[1][3] += av.y * bv.w;
            acc[2][0] += av.z * bv.x; acc[2][1] += av.z * bv.y;
            acc[2][2] += av.z * bv.z; acc[2][3] += av.z * bv.w;
            acc[3][0] += av.w * bv.x; acc[3][1] += av.w * bv.y;
            acc[3][2] += av.w * bv.z; acc[3][3] += av.w * bv.w;
        }
        __syncthreads();
    }

    float b0 = 0.f, b1 = 0.f, b2 = 0.f, b3 = 0.f;
    if (bias) {
        const int col = bcol + (tx << 2);
        b0 = bias[col]; b1 = bias[col + 1]; b2 = bias[col + 2]; b3 = bias[col + 3];
    }
    #pragma unroll
    for (int i = 0; i < 4; ++i) {
        const int row = brow + (ty << 2) + i;
        float4 o;
        o.x = acc[i][0] + b0; o.y = acc[i][1] + b1;
        o.z = acc[i][2] + b2; o.w = acc[i][3] + b3;
        *reinterpret_cast<float4*>(&C[(size_t)row * ldc + bcol + (tx << 2)]) = o;
    }
}

// ---------------- fused masked attention (fp32, length-aware) ----------------
// One block per (local batch, head, 32-row q-chunk).
// Exactness: keys j>=len have softmax weight 0 in the reference, so key-chunks
// with base >= len contribute nothing -> loop bound n_kc. Query rows q>=len are
// never consumed downstream (masked as keys; excluded from pooling) -> write 0.
__global__ __launch_bounds__(256) void attn_kernel(
    const float* __restrict__ qkv, const int* __restrict__ lengths,
    float* __restrict__ out, int b0)
{
    const int bid = blockIdx.x;
    const int lb  = bid >> 4;
    const int h   = (bid >> 2) & 3;
    const int qc  = bid & 3;
    const int len = lengths[b0 + lb];
    const int tid = threadIdx.x;

    const size_t rowbase = (size_t)lb * L_SEQ;
    const int q0 = qc * 32;

    // early-exit: padded query rows -> deterministic zeros (finite, unused);
    // block-uniform branch, exits before any __syncthreads().
    if (q0 >= len) {
        const int oi  = tid >> 3;
        const int oc0 = (tid & 7) << 3;
        float4 z = {0.f, 0.f, 0.f, 0.f};
        float* dst = &out[(rowbase + q0 + oi) * EMB + h * DH + oc0];
        *reinterpret_cast<float4*>(dst)     = z;
        *reinterpret_cast<float4*>(dst + 4) = z;
        return;
    }
    const int n_kc = (len + 31) >> 5;      // active key chunks

    __shared__ float Qs[32][DH + 4];
    __shared__ float Kt[DH][36];
    __shared__ float Vs[32][DH + 4];
    __shared__ float Ss[32][L_SEQ + 4];

    {
        const int r  = tid >> 4;
        const int c4 = (tid & 15) << 2;
        #pragma unroll
        for (int rr = 0; rr < 2; ++rr) {
            const int row = r + (rr << 4);
            float4 v = *reinterpret_cast<const float4*>(
                &qkv[(rowbase + q0 + row) * QKV3 + h * DH + c4]);
            v.x *= 0.125f; v.y *= 0.125f; v.z *= 0.125f; v.w *= 0.125f;
            *reinterpret_cast<float4*>(&Qs[row][c4]) = v;
        }
    }

    // ---- S = Q K^T over active key chunks ----
    for (int kc = 0; kc < n_kc; ++kc) {
        {
            const int r  = tid >> 4;
            const int c4 = (tid & 15) << 2;
            #pragma unroll
            for (int rr = 0; rr < 2; ++rr) {
                const int row = r + (rr << 4);
                const float4 v = *reinterpret_cast<const float4*>(
                    &qkv[(rowbase + kc * 32 + row) * QKV3 + EMB + h * DH + c4]);
                Kt[c4 + 0][row] = v.x;
                Kt[c4 + 1][row] = v.y;
                Kt[c4 + 2][row] = v.z;
                Kt[c4 + 3][row] = v.w;
            }
        }
        __syncthreads();
        const int si  = tid >> 3;
        const int sj0 = (tid & 7) << 2;
        float s0 = 0.f, s1 = 0.f, s2 = 0.f, s3 = 0.f;
        #pragma unroll
        for (int d = 0; d < DH; ++d) {
            const float qv = Qs[si][d];
            const float4 kv = *reinterpret_cast<const float4*>(&Kt[d][sj0]);
            s0 += qv * kv.x; s1 += qv * kv.y; s2 += qv * kv.z; s3 += qv * kv.w;
        }
        Ss[si][kc * 32 + sj0 + 0] = s0;
        Ss[si][kc * 32 + sj0 + 1] = s1;
        Ss[si][kc * 32 + sj0 + 2] = s2;
        Ss[si][kc * 32 + sj0 + 3] = s3;
        __syncthreads();
    }

    // ---- masked softmax, 8 threads per row (reads guarded by j<len) ----
    {
        const int r    = tid >> 3;
        const int lane = tid & 7;
        float m = -3.0e38f;
        #pragma unroll
        for (int jj = 0; jj < 16; ++jj) {
            const int j = lane + (jj << 3);
            if (j < len) m = fmaxf(m, Ss[r][j]);
        }
        #pragma unroll
        for (int o = 1; o < 8; o <<= 1) m = fmaxf(m, __shfl_xor(m, o, 8));
        float sum = 0.f;
        float ev[16];
        #pragma unroll
        for (int jj = 0; jj < 16; ++jj) {
            const int j = lane + (jj << 3);
            float e = 0.f;
            if (j < len) { e = __expf(Ss[r][j] - m); }
            ev[jj] = e;
            sum += e;
        }
        #pragma unroll
        for (int o = 1; o < 8; o <<= 1) sum += __shfl_xor(sum, o, 8);
        const float inv = 1.f / sum;
        #pragma unroll
        for (int jj = 0; jj < 16; ++jj) {
            const int j = lane + (jj << 3);
            Ss[r][j] = ev[jj] * inv;
        }
    }
    __syncthreads();

    // ---- O = P V over active value chunks (P=0 beyond len) ----
    const int oi  = tid >> 3;
    const int oc0 = (tid & 7) << 3;
    float o[8] = {0.f, 0.f, 0.f, 0.f, 0.f, 0.f, 0.f, 0.f};
    for (int kc = 0; kc < n_kc; ++kc) {
        {
            const int r  = tid >> 4;
            const int c4 = (tid & 15) << 2;
            #pragma unroll
            for (int rr = 0; rr < 2; ++rr) {
                const int row = r + (rr << 4);
                *reinterpret_cast<float4*>(&Vs[row][c4]) =
                    *reinterpret_cast<const float4*>(
                        &qkv[(rowbase + kc * 32 + row) * QKV3 + 2 * EMB + h * DH + c4]);
            }
        }
        __syncthreads();
        #pragma unroll
        for (int kk = 0; kk < 32; ++kk) {
            const float p = Ss[oi][kc * 32 + kk];
            const float4 v0 = *reinterpret_cast<const float4*>(&Vs[kk][oc0]);
            const float4 v1 = *reinterpret_cast<const float4*>(&Vs[kk][oc0 + 4]);
            o[0] += p * v0.x; o[1] += p * v0.y; o[2] += p * v0.z; o[3] += p * v0.w;
            o[4] += p * v1.x; o[5] += p * v1.y; o[6] += p * v1.z; o[7] += p * v1.w;
        }
        __syncthreads();
    }
    {
        float4 w0, w1;
        w0.x = o[0]; w0.y = o[1]; w0.z = o[2]; w0.w = o[3];
        w1.x = o[4]; w1.y = o[5]; w1.z = o[6]; w1.w = o[7];
        float* dst = &out[(rowbase + q0 + oi) * EMB + h * DH + oc0];
        *reinterpret_cast<float4*>(dst)     = w0;
        *reinterpret_cast<float4*>(dst + 4) = w1;
    }
}

// ---------------- LayerNorm: one wave per row, 4 rows/block ----------------
__global__ __launch_bounds__(256) void ln_kernel(
    const float* __restrict__ x, const float* __restrict__ res,
    const float* __restrict__ bias, const float* __restrict__ g,
    const float* __restrict__ beta, float* __restrict__ out, int relu)
{
    const int lane = threadIdx.x & 63;
    const int w    = threadIdx.x >> 6;
    const size_t row = (size_t)blockIdx.x * 4 + w;
    const int c = lane << 2;

    float4 v = *reinterpret_cast<const float4*>(&x[row * 256 + c]);
    if (res) {
        const float4 r = *reinterpret_cast<const float4*>(&res[row * 256 + c]);
        v.x += r.x; v.y += r.y; v.z += r.z; v.w += r.w;
    }
    if (bias) {
        const float4 b = *reinterpret_cast<const float4*>(&bias[c]);
        v.x += b.x; v.y += b.y; v.z += b.z; v.w += b.w;
    }
    float s = v.x + v.y + v.z + v.w;
    #pragma unroll
    for (int o = 32; o >= 1; o >>= 1) s += __shfl_xor(s, o, 64);
    const float mu = s * (1.f / 256.f);
    const float dx = v.x - mu, dy = v.y - mu, dz = v.z - mu, dw = v.w - mu;
    float q = dx * dx + dy * dy + dz * dz + dw * dw;
    #pragma unroll
    for (int o = 32; o >= 1; o >>= 1) q += __shfl_xor(q, o, 64);
    const float rs = rsqrtf(q * (1.f / 256.f) + 1e-5f);
    const float4 gg = *reinterpret_cast<const float4*>(&g[c]);
    const float4 bb = *reinterpret_cast<const float4*>(&beta[c]);
    float4 o4;
    o4.x = dx * rs * gg.x + bb.x;
    o4.y = dy * rs * gg.y + bb.y;
    o4.z = dz * rs * gg.z + bb.z;
    o4.w = dw * rs * gg.w + bb.w;
    if (relu) {
        o4.x = fmaxf(o4.x, 0.f); o4.y = fmaxf(o4.y, 0.f);
        o4.z = fmaxf(o4.z, 0.f); o4.w = fmaxf(o4.w, 0.f);
    }
    *reinterpret_cast<float4*>(&out[row * 256 + c]) = o4;
}

// ---------------- masked mean pooling ----------------
__global__ __launch_bounds__(256) void pool_kernel(
    const float* __restrict__ h, const int* __restrict__ lengths,
    float* __restrict__ pooled)
{
    const int b = blockIdx.x;
    const int c = threadIdx.x;
    const int len = lengths[b];
    float s = 0.f;
    for (int l = 0; l < len; ++l)
        s += h[((size_t)b * L_SEQ + l) * EMB + c];
    pooled[(size_t)b * EMB + c] = s / (float)len;
}

// ---------------- GAT: per-node attention coefficients ----------------
__global__ __launch_bounds__(256) void gat_sd_kernel(
    const float* __restrict__ xh, const float* __restrict__ asrc,
    const float* __restrict__ adst, float* __restrict__ sbuf,
    float* __restrict__ dbuf)
{
    const int n  = blockIdx.x;
    const int hd = threadIdx.x >> 6;
    const int d  = threadIdx.x & 63;
    const float xv = xh[(size_t)n * GOUT + hd * GHID + d];
    float sv = xv * asrc[hd * GHID + d];
    float dv = xv * adst[hd * GHID + d];
    #pragma unroll
    for (int o = 32; o >= 1; o >>= 1) {
        sv += __shfl_down(sv, o, 64);
        dv += __shfl_down(dv, o, 64);
    }
    if (d == 0) {
        sbuf[n * GHEADS + hd] = sv;
        dbuf[n * GHEADS + hd] = dv;
    }
}

// ---------------- CSR build (once per call; shared by both GAT layers) ----------------
__global__ __launch_bounds__(256) void csr_count(
    const int* __restrict__ ei, int* __restrict__ deg)
{
    const int e = blockIdx.x * 256 + threadIdx.x;
    if (e < NEDGE) atomicAdd(&deg[ei[NEDGE + e]], 1);
}

__global__ __launch_bounds__(1024) void csr_scan(
    const int* __restrict__ deg, int* __restrict__ offs, int* __restrict__ cursor)
{
    __shared__ int tmp[1024];
    const int t = threadIdx.x;
    const int v = deg[t];
    tmp[t] = v;
    __syncthreads();
    #pragma unroll
    for (int o = 1; o < 1024; o <<= 1) {
        const int x = (t >= o) ? tmp[t - o] : 0;
        __syncthreads();
        tmp[t] += x;
        __syncthreads();
    }
    const int excl = tmp[t] - v;
    offs[t]   = excl;
    cursor[t] = excl;
    if (t == 1023) offs[1024] = tmp[1023];
}

__global__ __launch_bounds__(256) void csr_fill(
    const int* __restrict__ ei, int* __restrict__ cursor, int* __restrict__ esrc)
{
    const int e = blockIdx.x * 256 + threadIdx.x;
    if (e < NEDGE) {
        const int dst = ei[NEDGE + e];
        const int pos = atomicAdd(&cursor[dst], 1);
        esrc[pos] = ei[e];    // store src id directly (edge identity not needed)
    }
}

// ---------------- GAT gather: block = dst node, thread = feature ----------------
// out = (sum_e ee*xh[src])/(sum_e ee + 1e-16)  ==  reference segment softmax+sum.
__global__ __launch_bounds__(256) void gat_gather(
    const int* __restrict__ esrc, const int* __restrict__ offs,
    const float* __restrict__ sbuf, const float* __restrict__ dbuf,
    const float* __restrict__ xh, float* __restrict__ outb)
{
    const int n = blockIdx.x;
    const int f = threadIdx.x;
    const int h = f >> 6;
    const int beg = offs[n], end = offs[n + 1];
    const float dv = dbuf[n * GHEADS + h];

    float m = -3.0e38f;
    for (int i = beg; i < end; ++i) {
        const int src = esrc[i];
        float e = sbuf[src * GHEADS + h] + dv;
        e = e > 0.f ? e : 0.2f * e;
        m = fmaxf(m, e);
    }
    float sum = 0.f, acc = 0.f;
    for (int i = beg; i < end; ++i) {
        const int src = esrc[i];
        float e = sbuf[src * GHEADS + h] + dv;
        e = e > 0.f ? e : 0.2f * e;
        const float ee = __expf(e - m);
        sum += ee;
        acc += ee * xh[(size_t)src * GOUT + f];
    }
    outb[(size_t)n * GOUT + f] = acc / (sum + 1e-16f);
}

// ---------------- final FC ----------------
__global__ __launch_bounds__(256) void fc_kernel(
    const float* __restrict__ g, const float* __restrict__ w,
    const float* __restrict__ b, float* __restrict__ out)
{
    const int node = blockIdx.x * 16 + (threadIdx.x >> 4);
    const int c    = threadIdx.x & 15;
    float s = 0.f;
    for (int k = 0; k < 256; ++k)
        s += g[(size_t)node * 256 + k] * w[k * NCLS + c];
    out[node * NCLS + c] = s + b[c];
}

// ---------------- host orchestration ----------------
extern "C" void kernel_launch(void* const* d_in, const int* in_sizes, int n_in,
                              void* d_out, int out_size, void* d_ws, size_t ws_size,
                              hipStream_t stream)
{
    const float* x        = (const float*)d_in[0];
    const int*   lengths  = (const int*)d_in[1];
    const int*   eidx     = (const int*)d_in[2];
    const float* in_w     = (const float*)d_in[3];
    const float* in_b     = (const float*)d_in[4];
    const float* wqkv[2]  = {(const float*)d_in[5], (const float*)d_in[9]};
    const float* bqkv[2]  = {(const float*)d_in[6], (const float*)d_in[10]};
    const float* wo[2]    = {(const float*)d_in[7], (const float*)d_in[11]};
    const float* bo[2]    = {(const float*)d_in[8], (const float*)d_in[12]};
    const float* ln_g[2]  = {(const float*)d_in[13], (const float*)d_in[15]};
    const float* ln_b[2]  = {(const float*)d_in[14], (const float*)d_in[16]};
    const float* gat_w[2]    = {(const float*)d_in[17], (const float*)d_in[21]};
    const float* gat_asrc[2] = {(const float*)d_in[18], (const float*)d_in[22]};
    const float* gat_adst[2] = {(const float*)d_in[19], (const float*)d_in[23]};
    const float* gat_bias[2] = {(const float*)d_in[20], (const float*)d_in[24]};
    const float* lng_g[2] = {(const float*)d_in[25], (const float*)d_in[27]};
    const float* lng_b[2] = {(const float*)d_in[26], (const float*)d_in[28]};
    const float* fc_w     = (const float*)d_in[29];
    const float* fc_b     = (const float*)d_in[30];
    float* outp = (float*)d_out;

    // ---- workspace layout (floats) ----
    float* W = (float*)d_ws;
    float* Hbuf   = W;                       // 131072*256
    float* QKVc   = Hbuf + (size_t)33554432; // 16384*768
    float* Ac     = QKVc + (size_t)12582912; // 16384*256
    float* Pc     = Ac   + (size_t)4194304;  // 16384*256
    float* pooled = Pc   + (size_t)4194304;  // 1024*256
    float* xh     = pooled + (size_t)262144;
    float* g1     = xh   + (size_t)262144;
    float* gacc   = g1   + (size_t)262144;
    float* sbuf   = gacc + (size_t)262144;   // 4096
    float* dbuf   = sbuf + 4096;             // 4096
    // CSR area (ints)
    int* deg    = (int*)(dbuf + 4096);       // 1024
    int* offs   = deg + 1024;                // 1025 (padded to 1056)
    int* cursor = offs + 1056;               // 1024
    int* esrc   = cursor + 1024;             // 16384
    // bf16 hi/lo transposed-weight area
    ushort_t* us = (ushort_t*)(esrc + 16384);
    ushort_t* inwtH   = us;                  // 256*64
    ushort_t* inwtL   = inwtH + 16384;
    ushort_t* qkvtH0  = inwtL + 16384;       // 768*256
    ushort_t* qkvtL0  = qkvtH0 + 196608;
    ushort_t* qkvtH1  = qkvtL0 + 196608;
    ushort_t* qkvtL1  = qkvtH1 + 196608;
    ushort_t* wotH0   = qkvtL1 + 196608;     // 256*256
    ushort_t* wotL0   = wotH0 + 65536;
    ushort_t* wotH1   = wotL0 + 65536;
    ushort_t* wotL1   = wotH1 + 65536;
    ushort_t* qkvtH[2] = {qkvtH0, qkvtH1};
    ushort_t* qkvtL[2] = {qkvtL0, qkvtL1};
    ushort_t* wotH[2]  = {wotH0, wotH1};
    ushort_t* wotL[2]  = {wotL0, wotL1};

    // ---- per-call weight transpose + split ----
    wsplit_kernel<<<(INSZ * EMB + 255) / 256, 256, 0, stream>>>(
        in_w, inwtH, inwtL, INSZ, EMB);
    for (int l = 0; l < 2; ++l) {
        wsplit_kernel<<<(EMB * QKV3 + 255) / 256, 256, 0, stream>>>(
            wqkv[l], qkvtH[l], qkvtL[l], EMB, QKV3);
        wsplit_kernel<<<(EMB * EMB + 255) / 256, 256, 0, stream>>>(
            wo[l], wotH[l], wotL[l], EMB, EMB);
    }

    // ---- CSR build (shared by both GAT layers) ----
    hipMemsetAsync(deg, 0, 1024 * sizeof(int), stream);
    csr_count<<<NEDGE / 256, 256, 0, stream>>>(eidx, deg);
    csr_scan<<<1, 1024, 0, stream>>>(deg, offs, cursor);
    csr_fill<<<NEDGE / 256, 256, 0, stream>>>(eidx, cursor, esrc);

    // ---- input projection ----
    gemm_mfma_split<<<dim3(EMB / 128, (B_SZ * L_SEQ) / 128), 256, 0, stream>>>(
        x, inwtH, inwtL, in_b, Hbuf, INSZ, INSZ, EMB);

    // ---- two transformer layers, chunked over batch ----
    for (int layer = 0; layer < 2; ++layer) {
        for (int ck = 0; ck < NCHUNK; ++ck) {
            float* Hc = Hbuf + (size_t)ck * ROWS_CHUNK * EMB;
            gemm_mfma_split<<<dim3(QKV3 / 128, ROWS_CHUNK / 128), 256, 0, stream>>>(
                Hc, qkvtH[layer], qkvtL[layer], bqkv[layer], QKVc,
                EMB, EMB, QKV3);
            attn_kernel<<<BCHUNK * NH * 4, 256, 0, stream>>>(
                QKVc, lengths, Ac, ck * BCHUNK);
            gemm_mfma_split<<<dim3(EMB / 128, ROWS_CHUNK / 128), 256, 0, stream>>>(
                Ac, wotH[layer], wotL[layer], bo[layer], Pc,
                EMB, EMB, EMB);
            ln_kernel<<<ROWS_CHUNK / 4, 256, 0, stream>>>(
                Hc, Pc, nullptr, ln_g[layer], ln_b[layer], Hc, 0);
        }
    }

    // ---- masked mean pooling ----
    pool_kernel<<<B_SZ, 256, 0, stream>>>(Hbuf, lengths, pooled);

    // ---- two GAT layers (CSR gather, no atomics) ----
    const float* gin = pooled;
    float* gout_ln[2] = {g1, pooled};
    for (int layer = 0; layer < 2; ++layer) {
        gemm_bias<<<dim3(GOUT / BN, B_SZ / BM), 256, 0, stream>>>(
            gin, gat_w[layer], nullptr, xh, B_SZ, GOUT, GOUT, GOUT, GOUT, GOUT);
        gat_sd_kernel<<<B_SZ, 256, 0, stream>>>(
            xh, gat_asrc[layer], gat_adst[layer], sbuf, dbuf);
        gat_gather<<<B_SZ, 256, 0, stream>>>(
            esrc, offs, sbuf, dbuf, xh, gacc);
        ln_kernel<<<B_SZ / 4, 256, 0, stream>>>(
            gacc, nullptr, gat_bias[layer], lng_g[layer], lng_b[layer],
            gout_ln[layer], 1);
        gin = gout_ln[layer];
    }

    // ---- final FC ----
    fc_kernel<<<B_SZ / 16, 256, 0, stream>>>(pooled, fc_w, fc_b, outp);
}

// Round 13
// 1990.902 us; speedup vs baseline: 1.4632x; 1.0438x over previous
//
#include <hip/hip_runtime.h>
#include <hip/hip_bf16.h>
#include <cstdint>
#include <cstddef>

// ---------------- problem constants ----------------
#define B_SZ    1024
#define L_SEQ   128
#define INSZ    64
#define EMB     256
#define NH      4
#define DH      64
#define QKV3    768
#define NEDGE   16384
#define GHEADS  4
#define GHID    64
#define GOUT    256
#define NCLS    16

#define NCHUNK     8
#define BCHUNK     (B_SZ / NCHUNK)        // 128 batches per chunk
#define ROWS_CHUNK (BCHUNK * L_SEQ)       // 16384 rows per chunk

typedef unsigned short ushort_t;
typedef short bf16x8 __attribute__((ext_vector_type(8)));      // 8 bf16 in 4 VGPRs
typedef float f32x4 __attribute__((ext_vector_type(4)));
typedef ushort_t us4 __attribute__((ext_vector_type(4)));
typedef ushort_t us8 __attribute__((ext_vector_type(8)));

__device__ __forceinline__ ushort_t f32_to_bf16_rne(float x) {
    unsigned u = __float_as_uint(x);
    unsigned r = u + 0x7FFFu + ((u >> 16) & 1u);
    return (ushort_t)(r >> 16);
}
__device__ __forceinline__ float bf16u_to_f32(ushort_t h) {
    return __uint_as_float(((unsigned)h) << 16);
}

// ---------------- weight transpose + fp32->bf16 hi/lo split ----------------
__global__ __launch_bounds__(256) void wsplit_kernel(
    const float* __restrict__ W, ushort_t* __restrict__ WtH,
    ushort_t* __restrict__ WtL, int K, int N)
{
    const int t = blockIdx.x * 256 + threadIdx.x;
    if (t >= K * N) return;
    const int n = t / K, k = t - n * K;
    const float x = W[(size_t)k * N + n];
    const ushort_t hi = f32_to_bf16_rne(x);
    const ushort_t lo = f32_to_bf16_rne(x - bf16u_to_f32(hi));
    WtH[t] = hi;
    WtL[t] = lo;
}

// ---------------- MFMA split-bf16 GEMM (templated tile) ----------------
// C = A@B + bias; A fp32 [M][K], B pre-split bf16 [N][K], C fp32.
// 3-term split: hi*hi + lo*hi + hi*lo => ~1e-4 relative accuracy.
// R8 changes vs R5 (counter-driven): (1) C staged through LDS and flushed as
// float4 rows (fixes 3.1x write amplification: WRITE_SIZE 158MB for 50MB of C);
// (2) smaller N-tile => 2x grid (occupancy was 17%, 3 blocks/CU);
// (3) bijective XCD swizzle for A-panel L2 locality.
#define AKP 40   // padded LDS K stride (bf16): 80B rows -> <=2-way b128 frag reads

template<int TBM, int TBN>
__global__ __launch_bounds__(256) void gemm_mfma_split_t(
    const float* __restrict__ A, const ushort_t* __restrict__ BtH,
    const ushort_t* __restrict__ BtL, const float* __restrict__ bias,
    float* __restrict__ C, int K, int lda, int ldc)
{
    constexpr int A_EL  = TBM * AKP;          // ushorts per A array
    constexpr int B_EL  = TBN * AKP;
    constexpr int CLDW  = TBN + 4;            // padded C-stage row (floats)
    constexpr int STAGE_BYTES = (2 * A_EL + 2 * B_EL) * 2;
    constexpr int CST_BYTES   = 64 * CLDW * 4;
    constexpr int RAW_BYTES   = STAGE_BYTES > CST_BYTES ? STAGE_BYTES : CST_BYTES;
    __shared__ __attribute__((aligned(16))) char raw[RAW_BYTES];
    ushort_t* AsH = (ushort_t*)raw;
    ushort_t* AsL = AsH + A_EL;
    ushort_t* BsH = AsL + A_EL;
    ushort_t* BsL = BsH + B_EL;
    float*    Cst = (float*)raw;              // reused after K-loop

    const int tid  = threadIdx.x;
    const int lane = tid & 63;
    const int wv   = tid >> 6;
    const int wm   = (wv >> 1) * (TBM / 2);   // wave row offset
    const int wn   = (wv & 1) * (TBN / 2);    // wave col offset
    const int fr   = lane & 15;
    const int fk   = (lane >> 4) << 3;
    constexpr int MI = TBM / 32;              // 16-row frags per wave
    constexpr int NJ = TBN / 32;              // 16-col frags per wave

    // bijective XCD swizzle (m204): consecutive orig ids -> same XCD,
    // so N-tiles sharing an A row-panel co-reside in one XCD's L2.
    const int nwg  = gridDim.x * gridDim.y;
    const int orig = blockIdx.y * gridDim.x + blockIdx.x;
    const int q8 = nwg >> 3, r8 = nwg & 7;
    const int xcd = orig & 7, lid = orig >> 3;
    const int wgid = (xcd < r8 ? xcd * (q8 + 1) : r8 * (q8 + 1) + (xcd - r8) * q8) + lid;
    const int bx = wgid % gridDim.x;
    const int by = wgid / gridDim.x;
    const size_t brow = (size_t)by * TBM;
    const int    bcol = bx * TBN;

    const int ar  = tid >> 3;                 // 0..31 (A stage row)
    const int ac  = (tid & 7) << 2;           // 0..28 (A stage k, 4 floats)
    const int brn = tid >> 2;                 // 0..63 (B stage row)
    const int bk  = (tid & 3) << 3;           // 0/8/16/24 (B stage k, 8 bf16)

    f32x4 acc[MI][NJ] = {};

    for (int k0 = 0; k0 < K; k0 += 32) {
        // ---- stage A: TBMx32 fp32 -> hi/lo bf16 ----
        #pragma unroll
        for (int p = 0; p < TBM / 32; ++p) {
            const int row = p * 32 + ar;
            const float4 v = *reinterpret_cast<const float4*>(
                &A[(brow + row) * lda + k0 + ac]);
            const ushort_t h0 = f32_to_bf16_rne(v.x);
            const ushort_t h1 = f32_to_bf16_rne(v.y);
            const ushort_t h2 = f32_to_bf16_rne(v.z);
            const ushort_t h3 = f32_to_bf16_rne(v.w);
            const ushort_t l0 = f32_to_bf16_rne(v.x - bf16u_to_f32(h0));
            const ushort_t l1 = f32_to_bf16_rne(v.y - bf16u_to_f32(h1));
            const ushort_t l2 = f32_to_bf16_rne(v.z - bf16u_to_f32(h2));
            const ushort_t l3 = f32_to_bf16_rne(v.w - bf16u_to_f32(h3));
            us4 hv = {h0, h1, h2, h3};
            us4 lv = {l0, l1, l2, l3};
            *reinterpret_cast<us4*>(&AsH[row * AKP + ac]) = hv;
            *reinterpret_cast<us4*>(&AsL[row * AKP + ac]) = lv;
        }
        // ---- stage B: TBNx32 bf16 (pre-split [N][K]) ----
        #pragma unroll
        for (int p = 0; p < TBN / 64; ++p) {
            const int row = p * 64 + brn;
            const size_t bb = (size_t)(bcol + row) * K + k0 + bk;
            *reinterpret_cast<us8*>(&BsH[row * AKP + bk]) =
                *reinterpret_cast<const us8*>(&BtH[bb]);
            *reinterpret_cast<us8*>(&BsL[row * AKP + bk]) =
                *reinterpret_cast<const us8*>(&BtL[bb]);
        }
        __syncthreads();

        bf16x8 aH[MI], aL[MI], bH[NJ], bL[NJ];
        #pragma unroll
        for (int i = 0; i < MI; ++i) {
            aH[i] = *reinterpret_cast<const bf16x8*>(&AsH[(wm + (i << 4) + fr) * AKP + fk]);
            aL[i] = *reinterpret_cast<const bf16x8*>(&AsL[(wm + (i << 4) + fr) * AKP + fk]);
        }
        #pragma unroll
        for (int j = 0; j < NJ; ++j) {
            bH[j] = *reinterpret_cast<const bf16x8*>(&BsH[(wn + (j << 4) + fr) * AKP + fk]);
            bL[j] = *reinterpret_cast<const bf16x8*>(&BsL[(wn + (j << 4) + fr) * AKP + fk]);
        }
        #pragma unroll
        for (int i = 0; i < MI; ++i) {
            #pragma unroll
            for (int j = 0; j < NJ; ++j) {
                acc[i][j] = __builtin_amdgcn_mfma_f32_16x16x32_bf16(
                    aH[i], bH[j], acc[i][j], 0, 0, 0);
                acc[i][j] = __builtin_amdgcn_mfma_f32_16x16x32_bf16(
                    aL[i], bH[j], acc[i][j], 0, 0, 0);
                acc[i][j] = __builtin_amdgcn_mfma_f32_16x16x32_bf16(
                    aH[i], bL[j], acc[i][j], 0, 0, 0);
            }
        }
        __syncthreads();
    }

    // ---- epilogue: stage 64-row groups in LDS, flush coalesced float4 ----
    const int r4 = (lane >> 4) << 2;
    #pragma unroll
    for (int g = 0; g < TBM / 64; ++g) {
        __syncthreads();
        if (wm / 64 == g) {
            #pragma unroll
            for (int i = 0; i < MI; ++i)
                #pragma unroll
                for (int j = 0; j < NJ; ++j)
                    #pragma unroll
                    for (int r = 0; r < 4; ++r)
                        Cst[(wm - g * 64 + (i << 4) + r4 + r) * CLDW
                            + wn + (j << 4) + fr] = acc[i][j][r];
        }
        __syncthreads();
        constexpr int F4R = TBN / 4;              // float4 per row
        constexpr int NF4 = 64 * F4R / 256;       // float4 per thread
        #pragma unroll
        for (int p = 0; p < NF4; ++p) {
            const int idx  = p * 256 + tid;
            const int row  = idx / F4R;
            const int colf = (idx % F4R) * 4;
            float4 v = *reinterpret_cast<const float4*>(&Cst[row * CLDW + colf]);
            if (bias) {
                const float4 bv = *reinterpret_cast<const float4*>(&bias[bcol + colf]);
                v.x += bv.x; v.y += bv.y; v.z += bv.z; v.w += bv.w;
            }
            *reinterpret_cast<float4*>(
                &C[(brow + g * 64 + row) * ldc + bcol + colf]) = v;
        }
    }
}

// ---------------- small tiled fp32 GEMM: 64x64x32 (GAT linear) ----------------
#define BM 64
#define BN 64
#define BK 32

__global__ __launch_bounds__(256) void gemm_bias(
    const float* __restrict__ A, const float* __restrict__ Bm,
    const float* __restrict__ bias, float* __restrict__ C,
    int M, int N, int K, int lda, int ldb, int ldc)
{
    __shared__ float As[BK][BM + 4];
    __shared__ float Bs[BK][BN];
    const int tid = threadIdx.x;
    const int tx = tid & 15, ty = tid >> 4;
    const int brow = blockIdx.y * BM, bcol = blockIdx.x * BN;

    float acc[4][4] = {{0.f, 0.f, 0.f, 0.f}, {0.f, 0.f, 0.f, 0.f},
                       {0.f, 0.f, 0.f, 0.f}, {0.f, 0.f, 0.f, 0.f}};

    for (int k0 = 0; k0 < K; k0 += BK) {
        {
            const int r  = tid >> 3;
            const int c4 = (tid & 7) << 2;
            #pragma unroll
            for (int rr = 0; rr < 2; ++rr) {
                const int row = r + (rr << 5);
                const float4 v = *reinterpret_cast<const float4*>(
                    &A[(size_t)(brow + row) * lda + k0 + c4]);
                As[c4 + 0][row] = v.x;
                As[c4 + 1][row] = v.y;
                As[c4 + 2][row] = v.z;
                As[c4 + 3][row] = v.w;
            }
        }
        {
            const int r  = tid >> 4;
            const int c4 = tx << 2;
            #pragma unroll
            for (int rr = 0; rr < 2; ++rr) {
                const int row = r + (rr << 4);
                *reinterpret_cast<float4*>(&Bs[row][c4]) =
                    *reinterpret_cast<const float4*>(
                        &Bm[(size_t)(k0 + row) * ldb + bcol + c4]);
            }
        }
        __syncthreads();
        #pragma unroll
        for (int k = 0; k < BK; ++k) {
            const float4 av = *reinterpret_cast<const float4*>(&As[k][ty << 2]);
            const float4 bv = *reinterpret_cast<const float4*>(&Bs[k][tx << 2]);
            acc[0][0] += av.x * bv.x; acc[0][1] += av.x * bv.y;
            acc[0][2] += av.x * bv.z; acc[0][3] += av.x * bv.w;
            acc[1][0] += av.y * bv.x; acc[1][1] += av.y * bv.y;
            acc[1][2] += av.y * bv.z; acc[1][3] += av.y * bv.w;
            acc[2][0] += av.z * bv.x; acc[2][1] += av.z * bv.y;
            acc[2][2] += av.z * bv.z; acc[2][3] += av.z * bv.w;
            acc[3][0] += av.w * bv.x; acc[3][1] += av.w * bv.y;
            acc[3][2] += av.w * bv.z; acc[3][3] += av.w * bv.w;
        }
        __syncthreads();
    }

    float b0 = 0.f, b1 = 0.f, b2 = 0.f, b3 = 0.f;
    if (bias) {
        const int col = bcol + (tx << 2);
        b0 = bias[col]; b1 = bias[col + 1]; b2 = bias[col + 2]; b3 = bias[col + 3];
    }
    #pragma unroll
    for (int i = 0; i < 4; ++i) {
        const int row = brow + (ty << 2) + i;
        float4 o;
        o.x = acc[i][0] + b0; o.y = acc[i][1] + b1;
        o.z = acc[i][2] + b2; o.w = acc[i][3] + b3;
        *reinterpret_cast<float4*>(&C[(size_t)row * ldc + bcol + (tx << 2)]) = o;
    }
}

// ---------------- fused masked attention (fp32, length-aware) ----------------
__global__ __launch_bounds__(256) void attn_kernel(
    const float* __restrict__ qkv, const int* __restrict__ lengths,
    float* __restrict__ out, int b0)
{
    const int bid = blockIdx.x;
    const int lb  = bid >> 4;
    const int h   = (bid >> 2) & 3;
    const int qc  = bid & 3;
    const int len = lengths[b0 + lb];
    const int tid = threadIdx.x;

    const size_t rowbase = (size_t)lb * L_SEQ;
    const int q0 = qc * 32;

    // early-exit: padded query rows -> deterministic zeros (finite, unused);
    // block-uniform branch, exits before any __syncthreads().
    if (q0 >= len) {
        const int oi  = tid >> 3;
        const int oc0 = (tid & 7) << 3;
        float4 z = {0.f, 0.f, 0.f, 0.f};
        float* dst = &out[(rowbase + q0 + oi) * EMB + h * DH + oc0];
        *reinterpret_cast<float4*>(dst)     = z;
        *reinterpret_cast<float4*>(dst + 4) = z;
        return;
    }
    const int n_kc = (len + 31) >> 5;      // active key chunks

    __shared__ float Qs[32][DH + 4];
    __shared__ float Kt[DH][36];
    __shared__ float Vs[32][DH + 4];
    __shared__ float Ss[32][L_SEQ + 4];

    {
        const int r  = tid >> 4;
        const int c4 = (tid & 15) << 2;
        #pragma unroll
        for (int rr = 0; rr < 2; ++rr) {
            const int row = r + (rr << 4);
            float4 v = *reinterpret_cast<const float4*>(
                &qkv[(rowbase + q0 + row) * QKV3 + h * DH + c4]);
            v.x *= 0.125f; v.y *= 0.125f; v.z *= 0.125f; v.w *= 0.125f;
            *reinterpret_cast<float4*>(&Qs[row][c4]) = v;
        }
    }

    for (int kc = 0; kc < n_kc; ++kc) {
        {
            const int r  = tid >> 4;
            const int c4 = (tid & 15) << 2;
            #pragma unroll
            for (int rr = 0; rr < 2; ++rr) {
                const int row = r + (rr << 4);
                const float4 v = *reinterpret_cast<const float4*>(
                    &qkv[(rowbase + kc * 32 + row) * QKV3 + EMB + h * DH + c4]);
                Kt[c4 + 0][row] = v.x;
                Kt[c4 + 1][row] = v.y;
                Kt[c4 + 2][row] = v.z;
                Kt[c4 + 3][row] = v.w;
            }
        }
        __syncthreads();
        const int si  = tid >> 3;
        const int sj0 = (tid & 7) << 2;
        float s0 = 0.f, s1 = 0.f, s2 = 0.f, s3 = 0.f;
        #pragma unroll
        for (int d = 0; d < DH; ++d) {
            const float qv = Qs[si][d];
            const float4 kv = *reinterpret_cast<const float4*>(&Kt[d][sj0]);
            s0 += qv * kv.x; s1 += qv * kv.y; s2 += qv * kv.z; s3 += qv * kv.w;
        }
        Ss[si][kc * 32 + sj0 + 0] = s0;
        Ss[si][kc * 32 + sj0 + 1] = s1;
        Ss[si][kc * 32 + sj0 + 2] = s2;
        Ss[si][kc * 32 + sj0 + 3] = s3;
        __syncthreads();
    }

    {
        const int r    = tid >> 3;
        const int lane = tid & 7;
        float m = -3.0e38f;
        #pragma unroll
        for (int jj = 0; jj < 16; ++jj) {
            const int j = lane + (jj << 3);
            if (j < len) m = fmaxf(m, Ss[r][j]);
        }
        #pragma unroll
        for (int o = 1; o < 8; o <<= 1) m = fmaxf(m, __shfl_xor(m, o, 8));
        float sum = 0.f;
        float ev[16];
        #pragma unroll
        for (int jj = 0; jj < 16; ++jj) {
            const int j = lane + (jj << 3);
            float e = 0.f;
            if (j < len) { e = __expf(Ss[r][j] - m); }
            ev[jj] = e;
            sum += e;
        }
        #pragma unroll
        for (int o = 1; o < 8; o <<= 1) sum += __shfl_xor(sum, o, 8);
        const float inv = 1.f / sum;
        #pragma unroll
        for (int jj = 0; jj < 16; ++jj) {
            const int j = lane + (jj << 3);
            Ss[r][j] = ev[jj] * inv;
        }
    }
    __syncthreads();

    const int oi  = tid >> 3;
    const int oc0 = (tid & 7) << 3;
    float o[8] = {0.f, 0.f, 0.f, 0.f, 0.f, 0.f, 0.f, 0.f};
    for (int kc = 0; kc < n_kc; ++kc) {
        {
            const int r  = tid >> 4;
            const int c4 = (tid & 15) << 2;
            #pragma unroll
            for (int rr = 0; rr < 2; ++rr) {
                const int row = r + (rr << 4);
                *reinterpret_cast<float4*>(&Vs[row][c4]) =
                    *reinterpret_cast<const float4*>(
                        &qkv[(rowbase + kc * 32 + row) * QKV3 + 2 * EMB + h * DH + c4]);
            }
        }
        __syncthreads();
        #pragma unroll
        for (int kk = 0; kk < 32; ++kk) {
            const float p = Ss[oi][kc * 32 + kk];
            const float4 v0 = *reinterpret_cast<const float4*>(&Vs[kk][oc0]);
            const float4 v1 = *reinterpret_cast<const float4*>(&Vs[kk][oc0 + 4]);
            o[0] += p * v0.x; o[1] += p * v0.y; o[2] += p * v0.z; o[3] += p * v0.w;
            o[4] += p * v1.x; o[5] += p * v1.y; o[6] += p * v1.z; o[7] += p * v1.w;
        }
        __syncthreads();
    }
    {
        float4 w0, w1;
        w0.x = o[0]; w0.y = o[1]; w0.z = o[2]; w0.w = o[3];
        w1.x = o[4]; w1.y = o[5]; w1.z = o[6]; w1.w = o[7];
        float* dst = &out[(rowbase + q0 + oi) * EMB + h * DH + oc0];
        *reinterpret_cast<float4*>(dst)     = w0;
        *reinterpret_cast<float4*>(dst + 4) = w1;
    }
}

// ---------------- LayerNorm: one wave per row, 4 rows/block ----------------
__global__ __launch_bounds__(256) void ln_kernel(
    const float* __restrict__ x, const float* __restrict__ res,
    const float* __restrict__ bias, const float* __restrict__ g,
    const float* __restrict__ beta, float* __restrict__ out, int relu)
{
    const int lane = threadIdx.x & 63;
    const int w    = threadIdx.x >> 6;
    const size_t row = (size_t)blockIdx.x * 4 + w;
    const int c = lane << 2;

    float4 v = *reinterpret_cast<const float4*>(&x[row * 256 + c]);
    if (res) {
        const float4 r = *reinterpret_cast<const float4*>(&res[row * 256 + c]);
        v.x += r.x; v.y += r.y; v.z += r.z; v.w += r.w;
    }
    if (bias) {
        const float4 b = *reinterpret_cast<const float4*>(&bias[c]);
        v.x += b.x; v.y += b.y; v.z += b.z; v.w += b.w;
    }
    float s = v.x + v.y + v.z + v.w;
    #pragma unroll
    for (int o = 32; o >= 1; o >>= 1) s += __shfl_xor(s, o, 64);
    const float mu = s * (1.f / 256.f);
    const float dx = v.x - mu, dy = v.y - mu, dz = v.z - mu, dw = v.w - mu;
    float q = dx * dx + dy * dy + dz * dz + dw * dw;
    #pragma unroll
    for (int o = 32; o >= 1; o >>= 1) q += __shfl_xor(q, o, 64);
    const float rs = rsqrtf(q * (1.f / 256.f) + 1e-5f);
    const float4 gg = *reinterpret_cast<const float4*>(&g[c]);
    const float4 bb = *reinterpret_cast<const float4*>(&beta[c]);
    float4 o4;
    o4.x = dx * rs * gg.x + bb.x;
    o4.y = dy * rs * gg.y + bb.y;
    o4.z = dz * rs * gg.z + bb.z;
    o4.w = dw * rs * gg.w + bb.w;
    if (relu) {
        o4.x = fmaxf(o4.x, 0.f); o4.y = fmaxf(o4.y, 0.f);
        o4.z = fmaxf(o4.z, 0.f); o4.w = fmaxf(o4.w, 0.f);
    }
    *reinterpret_cast<float4*>(&out[row * 256 + c]) = o4;
}

// ---------------- masked mean pooling ----------------
__global__ __launch_bounds__(256) void pool_kernel(
    const float* __restrict__ h, const int* __restrict__ lengths,
    float* __restrict__ pooled)
{
    const int b = blockIdx.x;
    const int c = threadIdx.x;
    const int len = lengths[b];
    float s = 0.f;
    for (int l = 0; l < len; ++l)
        s += h[((size_t)b * L_SEQ + l) * EMB + c];
    pooled[(size_t)b * EMB + c] = s / (float)len;
}

// ---------------- GAT: per-node attention coefficients ----------------
__global__ __launch_bounds__(256) void gat_sd_kernel(
    const float* __restrict__ xh, const float* __restrict__ asrc,
    const float* __restrict__ adst, float* __restrict__ sbuf,
    float* __restrict__ dbuf)
{
    const int n  = blockIdx.x;
    const int hd = threadIdx.x >> 6;
    const int d  = threadIdx.x & 63;
    const float xv = xh[(size_t)n * GOUT + hd * GHID + d];
    float sv = xv * asrc[hd * GHID + d];
    float dv = xv * adst[hd * GHID + d];
    #pragma unroll
    for (int o = 32; o >= 1; o >>= 1) {
        sv += __shfl_down(sv, o, 64);
        dv += __shfl_down(dv, o, 64);
    }
    if (d == 0) {
        sbuf[n * GHEADS + hd] = sv;
        dbuf[n * GHEADS + hd] = dv;
    }
}

// ---------------- CSR build (once per call; shared by both GAT layers) ----------------
__global__ __launch_bounds__(256) void csr_count(
    const int* __restrict__ ei, int* __restrict__ deg)
{
    const int e = blockIdx.x * 256 + threadIdx.x;
    if (e < NEDGE) atomicAdd(&deg[ei[NEDGE + e]], 1);
}

__global__ __launch_bounds__(1024) void csr_scan(
    const int* __restrict__ deg, int* __restrict__ offs, int* __restrict__ cursor)
{
    __shared__ int tmp[1024];
    const int t = threadIdx.x;
    const int v = deg[t];
    tmp[t] = v;
    __syncthreads();
    #pragma unroll
    for (int o = 1; o < 1024; o <<= 1) {
        const int x = (t >= o) ? tmp[t - o] : 0;
        __syncthreads();
        tmp[t] += x;
        __syncthreads();
    }
    const int excl = tmp[t] - v;
    offs[t]   = excl;
    cursor[t] = excl;
    if (t == 1023) offs[1024] = tmp[1023];
}

__global__ __launch_bounds__(256) void csr_fill(
    const int* __restrict__ ei, int* __restrict__ cursor, int* __restrict__ esrc)
{
    const int e = blockIdx.x * 256 + threadIdx.x;
    if (e < NEDGE) {
        const int dst = ei[NEDGE + e];
        const int pos = atomicAdd(&cursor[dst], 1);
        esrc[pos] = ei[e];    // store src id directly (edge identity not needed)
    }
}

// ---------------- GAT gather: block = dst node, thread = feature ----------------
__global__ __launch_bounds__(256) void gat_gather(
    const int* __restrict__ esrc, const int* __restrict__ offs,
    const float* __restrict__ sbuf, const float* __restrict__ dbuf,
    const float* __restrict__ xh, float* __restrict__ outb)
{
    const int n = blockIdx.x;
    const int f = threadIdx.x;
    const int h = f >> 6;
    const int beg = offs[n], end = offs[n + 1];
    const float dv = dbuf[n * GHEADS + h];

    float m = -3.0e38f;
    for (int i = beg; i < end; ++i) {
        const int src = esrc[i];
        float e = sbuf[src * GHEADS + h] + dv;
        e = e > 0.f ? e : 0.2f * e;
        m = fmaxf(m, e);
    }
    float sum = 0.f, acc = 0.f;
    for (int i = beg; i < end; ++i) {
        const int src = esrc[i];
        float e = sbuf[src * GHEADS + h] + dv;
        e = e > 0.f ? e : 0.2f * e;
        const float ee = __expf(e - m);
        sum += ee;
        acc += ee * xh[(size_t)src * GOUT + f];
    }
    outb[(size_t)n * GOUT + f] = acc / (sum + 1e-16f);
}

// ---------------- final FC ----------------
__global__ __launch_bounds__(256) void fc_kernel(
    const float* __restrict__ g, const float* __restrict__ w,
    const float* __restrict__ b, float* __restrict__ out)
{
    const int node = blockIdx.x * 16 + (threadIdx.x >> 4);
    const int c    = threadIdx.x & 15;
    float s = 0.f;
    for (int k = 0; k < 256; ++k)
        s += g[(size_t)node * 256 + k] * w[k * NCLS + c];
    out[node * NCLS + c] = s + b[c];
}

// ---------------- host orchestration ----------------
extern "C" void kernel_launch(void* const* d_in, const int* in_sizes, int n_in,
                              void* d_out, int out_size, void* d_ws, size_t ws_size,
                              hipStream_t stream)
{
    const float* x        = (const float*)d_in[0];
    const int*   lengths  = (const int*)d_in[1];
    const int*   eidx     = (const int*)d_in[2];
    const float* in_w     = (const float*)d_in[3];
    const float* in_b     = (const float*)d_in[4];
    const float* wqkv[2]  = {(const float*)d_in[5], (const float*)d_in[9]};
    const float* bqkv[2]  = {(const float*)d_in[6], (const float*)d_in[10]};
    const float* wo[2]    = {(const float*)d_in[7], (const float*)d_in[11]};
    const float* bo[2]    = {(const float*)d_in[8], (const float*)d_in[12]};
    const float* ln_g[2]  = {(const float*)d_in[13], (const float*)d_in[15]};
    const float* ln_b[2]  = {(const float*)d_in[14], (const float*)d_in[16]};
    const float* gat_w[2]    = {(const float*)d_in[17], (const float*)d_in[21]};
    const float* gat_asrc[2] = {(const float*)d_in[18], (const float*)d_in[22]};
    const float* gat_adst[2] = {(const float*)d_in[19], (const float*)d_in[23]};
    const float* gat_bias[2] = {(const float*)d_in[20], (const float*)d_in[24]};
    const float* lng_g[2] = {(const float*)d_in[25], (const float*)d_in[27]};
    const float* lng_b[2] = {(const float*)d_in[26], (const float*)d_in[28]};
    const float* fc_w     = (const float*)d_in[29];
    const float* fc_b     = (const float*)d_in[30];
    float* outp = (float*)d_out;

    // ---- workspace layout (floats) ----
    float* W = (float*)d_ws;
    float* Hbuf   = W;                       // 131072*256
    float* QKVc   = Hbuf + (size_t)33554432; // 16384*768
    float* Ac     = QKVc + (size_t)12582912; // 16384*256
    float* Pc     = Ac   + (size_t)4194304;  // 16384*256
    float* pooled = Pc   + (size_t)4194304;  // 1024*256
    float* xh     = pooled + (size_t)262144;
    float* g1     = xh   + (size_t)262144;
    float* gacc   = g1   + (size_t)262144;
    float* sbuf   = gacc + (size_t)262144;   // 4096
    float* dbuf   = sbuf + 4096;             // 4096
    // CSR area (ints)
    int* deg    = (int*)(dbuf + 4096);       // 1024
    int* offs   = deg + 1024;                // 1025 (padded to 1056)
    int* cursor = offs + 1056;               // 1024
    int* esrc   = cursor + 1024;             // 16384
    // bf16 hi/lo transposed-weight area
    ushort_t* us = (ushort_t*)(esrc + 16384);
    ushort_t* inwtH   = us;                  // 256*64
    ushort_t* inwtL   = inwtH + 16384;
    ushort_t* qkvtH0  = inwtL + 16384;       // 768*256
    ushort_t* qkvtL0  = qkvtH0 + 196608;
    ushort_t* qkvtH1  = qkvtL0 + 196608;
    ushort_t* qkvtL1  = qkvtH1 + 196608;
    ushort_t* wotH0   = qkvtL1 + 196608;     // 256*256
    ushort_t* wotL0   = wotH0 + 65536;
    ushort_t* wotH1   = wotL0 + 65536;
    ushort_t* wotL1   = wotH1 + 65536;
    ushort_t* qkvtH[2] = {qkvtH0, qkvtH1};
    ushort_t* qkvtL[2] = {qkvtL0, qkvtL1};
    ushort_t* wotH[2]  = {wotH0, wotH1};
    ushort_t* wotL[2]  = {wotL0, wotL1};

    // ---- per-call weight transpose + split ----
    wsplit_kernel<<<(INSZ * EMB + 255) / 256, 256, 0, stream>>>(
        in_w, inwtH, inwtL, INSZ, EMB);
    for (int l = 0; l < 2; ++l) {
        wsplit_kernel<<<(EMB * QKV3 + 255) / 256, 256, 0, stream>>>(
            wqkv[l], qkvtH[l], qkvtL[l], EMB, QKV3);
        wsplit_kernel<<<(EMB * EMB + 255) / 256, 256, 0, stream>>>(
            wo[l], wotH[l], wotL[l], EMB, EMB);
    }

    // ---- CSR build (shared by both GAT layers) ----
    hipMemsetAsync(deg, 0, 1024 * sizeof(int), stream);
    csr_count<<<NEDGE / 256, 256, 0, stream>>>(eidx, deg);
    csr_scan<<<1, 1024, 0, stream>>>(deg, offs, cursor);
    csr_fill<<<NEDGE / 256, 256, 0, stream>>>(eidx, cursor, esrc);

    // ---- input projection (128x64 tile; grid 4x1024) ----
    gemm_mfma_split_t<128, 64><<<dim3(EMB / 64, (B_SZ * L_SEQ) / 128), 256, 0, stream>>>(
        x, inwtH, inwtL, in_b, Hbuf, INSZ, INSZ, EMB);

    // ---- two transformer layers, chunked over batch ----
    for (int layer = 0; layer < 2; ++layer) {
        for (int ck = 0; ck < NCHUNK; ++ck) {
            float* Hc = Hbuf + (size_t)ck * ROWS_CHUNK * EMB;
            // QKV: 128x64 tile -> grid 12x128 = 1536 blocks (6/CU)
            gemm_mfma_split_t<128, 64><<<dim3(QKV3 / 64, ROWS_CHUNK / 128), 256, 0, stream>>>(
                Hc, qkvtH[layer], qkvtL[layer], bqkv[layer], QKVc,
                EMB, EMB, QKV3);
            attn_kernel<<<BCHUNK * NH * 4, 256, 0, stream>>>(
                QKVc, lengths, Ac, ck * BCHUNK);
            // out-proj: 64x64 tile -> grid 4x256 = 1024 blocks (4/CU)
            gemm_mfma_split_t<64, 64><<<dim3(EMB / 64, ROWS_CHUNK / 64), 256, 0, stream>>>(
                Ac, wotH[layer], wotL[layer], bo[layer], Pc,
                EMB, EMB, EMB);
            ln_kernel<<<ROWS_CHUNK / 4, 256, 0, stream>>>(
                Hc, Pc, nullptr, ln_g[layer], ln_b[layer], Hc, 0);
        }
    }

    // ---- masked mean pooling ----
    pool_kernel<<<B_SZ, 256, 0, stream>>>(Hbuf, lengths, pooled);

    // ---- two GAT layers (CSR gather, no atomics) ----
    const float* gin = pooled;
    float* gout_ln[2] = {g1, pooled};
    for (int layer = 0; layer < 2; ++layer) {
        gemm_bias<<<dim3(GOUT / BN, B_SZ / BM), 256, 0, stream>>>(
            gin, gat_w[layer], nullptr, xh, B_SZ, GOUT, GOUT, GOUT, GOUT, GOUT);
        gat_sd_kernel<<<B_SZ, 256, 0, stream>>>(
            xh, gat_asrc[layer], gat_adst[layer], sbuf, dbuf);
        gat_gather<<<B_SZ, 256, 0, stream>>>(
            esrc, offs, sbuf, dbuf, xh, gacc);
        ln_kernel<<<B_SZ / 4, 256, 0, stream>>>(
            gacc, nullptr, gat_bias[layer], lng_g[layer], lng_b[layer],
            gout_ln[layer], 1);
        gin = gout_ln[layer];
    }

    // ---- final FC ----
    fc_kernel<<<B_SZ / 16, 256, 0, stream>>>(pooled, fc_w, fc_b, outp);
}